// Round 1
// baseline (263.915 us; speedup 1.0000x reference)
//
#include <hip/hip_runtime.h>
#include <math.h>

#define SCALE_L2E 0.51006972157f   // (1/sqrt(8)) * log2(e) -- softmax done in exp2 domain
#define EPSV 1e-5f

typedef __attribute__((ext_vector_type(8))) short bf16x8;
typedef __attribute__((ext_vector_type(4))) float f32x4;
typedef __attribute__((ext_vector_type(16))) float f32x16;
typedef __attribute__((ext_vector_type(4))) int i32x4;
typedef __attribute__((ext_vector_type(2))) int i32x2;

static __device__ __forceinline__ unsigned short bfh(float f) {
    return (unsigned short)(__builtin_bit_cast(unsigned int, f) >> 16);
}
static __device__ __forceinline__ float bf2f(unsigned short s) {
    return __builtin_bit_cast(float, (unsigned int)s << 16);
}
static __device__ __forceinline__ int pack2(float lo, float hi) {
    return __builtin_amdgcn_perm(__builtin_bit_cast(unsigned int, hi),
                                 __builtin_bit_cast(unsigned int, lo), 0x07060302u);
}
#define LGKM0() __asm__ __volatile__("s_waitcnt lgkmcnt(0)" ::: "memory")

// ws layout: [0,8192) ushort wqk B-frags; [8192,40960) ushort W2ᵀ B-frags;
//            byte 81920: float bnA[64], bnB[64]
__global__ void prep_kernel(const float* __restrict__ w_qk,
                            const float* __restrict__ conv_w,
                            const float* __restrict__ conv_b,
                            const float* __restrict__ bn_g, const float* __restrict__ bn_b,
                            const float* __restrict__ bn_m, const float* __restrict__ bn_v,
                            unsigned short* __restrict__ ws) {
    int i = blockIdx.x * 256 + threadIdx.x;
    if (i < 8192) {
        // qk B-frag: frag(nt,ks): val = w_qk[k][n], k=ks*32+(l>>4)*8+j, n=nt*16+(l&15)
        int f = i >> 9, rem = i & 511, l = rem >> 3, j = rem & 7;
        int nt = f >> 1, ks = f & 1;
        int k = ks * 32 + (l >> 4) * 8 + j;
        int nn = nt * 16 + (l & 15);
        ws[i] = bfh(w_qk[k * 128 + nn]);
    } else if (i < 40960) {
        // W2ᵀ B-frag: frag(h,nt,ks): val = conv_w[h][o][c], c=ks*32+(l>>4)*8+j, o=nt*16+(l&15)
        int i2 = i - 8192;
        int g = i2 >> 9, rem = i2 & 511, l = rem >> 3, j = rem & 7;
        int h = g >> 3, nt = (g >> 1) & 3, ks = g & 1;
        int c = ks * 32 + (l >> 4) * 8 + j;
        int o = nt * 16 + (l & 15);
        ws[i] = bfh(conv_w[h * 4096 + o * 64 + c]);
    } else if (i < 41024) {
        int o = i - 40960;
        float gv = bn_g[o] * rsqrtf(bn_v[o] + EPSV);
        float bb = bn_b[o] - bn_m[o] * gv;
        float cb = 0.f;
        for (int h = 0; h < 8; h++) cb += conv_b[h * 64 + o];
        float* wsf = (float*)(ws + 40960);
        wsf[o] = gv;
        wsf[64 + o] = bb + cb * gv;
    }
}

// One WAVE per (n,t) tile; 4 waves/block; NO __syncthreads (all LDS is wave-private).
// Per-wave LDS 8192 B (block 32768 -> 5 blocks/CU = 20 waves/CU):
//   region A [0,4096):   qbuf[32][24]@0 + kbuf[32][24]@1536  (qk->dots)
//                        then FWT swizzled [64 rows][64 B]   (per-hh FW staging)
//   region B [4096,8192): mus[32]/rss[32] (transient) then Gh swizzled [2][32 rows][64 B]
// Swizzle: 16B storage block = logical_block ^ ((row>>2)&3); all accesses 16B/8B aligned.
__global__ __launch_bounds__(256, 5)
void sagc_kernel(const float* __restrict__ x,
                 const float* __restrict__ ln_g, const float* __restrict__ ln_b,
                 const float* __restrict__ b_qk,
                 const float* __restrict__ topo,
                 const unsigned short* __restrict__ ws,
                 float* __restrict__ out)
{
    __shared__ __align__(16) unsigned char smem[32768];
    const int tid = threadIdx.x;
    const int lane = tid & 63, wv = tid >> 6;
    const int l15 = lane & 15, quad = lane >> 4;
    const int r32 = lane & 31, hi = lane >> 5;

    unsigned char* my = smem + wv * 8192;
    unsigned short* qbuf = (unsigned short*)my;            // [32][24] u16
    unsigned short* kbuf = (unsigned short*)(my + 1536);   // [32][24] u16
    unsigned char*  fwb  = my;                             // FWT swizzled, 4096 B
    unsigned char*  ghb  = my + 4096;                      // Gh swizzled, 2 x 2048 B
    float*          mus  = (float*)(my + 4096);            // transient (pre-loop only)
    float*          rss  = mus + 32;

    const unsigned short* wqk = ws;
    const unsigned short* w2f = ws + 8192;
    const float* bnA = (const float*)(ws + 40960);
    const float* bnB = bnA + 64;

    const int tile = blockIdx.x * 4 + wv;
    const int n = tile >> 8, t = tile & 255;
    const float* xg = x + (size_t)n * 409600 + (size_t)t * 25;   // + c*6400 + v
    float* og = out + (size_t)n * 409600 + (size_t)t * 25;

    // ---- direct-register x load (no LDS staging): xf[mt][ks][j] = x[c][v], 0 at v>=25 ----
    float xf[2][2][8];
    #pragma unroll
    for (int mt = 0; mt < 2; mt++) {
        const int v = mt * 16 + l15;
        const bool ok = (v < 25);
        const float* xc = xg + v;
        #pragma unroll
        for (int ks = 0; ks < 2; ks++)
            #pragma unroll
            for (int j = 0; j < 8; j++) {
                int c = ks * 32 + quad * 8 + j;
                xf[mt][ks][j] = ok ? xc[c * 6400] : 0.f;
            }
    }

    // ---- pack x A-frags + squares ----
    bf16x8 xa[2][2], sqf[2][2];
    #pragma unroll
    for (int mt = 0; mt < 2; mt++)
        #pragma unroll
        for (int ks = 0; ks < 2; ks++) {
            i32x4 pa, ps;
            #pragma unroll
            for (int q = 0; q < 4; q++) {
                float a = xf[mt][ks][2 * q], b = xf[mt][ks][2 * q + 1];
                pa[q] = pack2(a, b);
                ps[q] = pack2(a * a, b * b);
            }
            xa[mt][ks]  = __builtin_bit_cast(bf16x8, pa);
            sqf[mt][ks] = __builtin_bit_cast(bf16x8, ps);
        }

    // ---- LN stats via MFMA (B = ones * 1/64) ----
    {
        i32x4 ones_i = {0x3C803C80, 0x3C803C80, 0x3C803C80, 0x3C803C80};
        bf16x8 onesf = __builtin_bit_cast(bf16x8, ones_i);
        f32x4 z4 = {0.f, 0.f, 0.f, 0.f};
        f32x4 dmu[2], ds2[2];
        #pragma unroll
        for (int mt = 0; mt < 2; mt++) {
            dmu[mt] = __builtin_amdgcn_mfma_f32_16x16x32_bf16(xa[mt][0], onesf, z4, 0, 0, 0);
            dmu[mt] = __builtin_amdgcn_mfma_f32_16x16x32_bf16(xa[mt][1], onesf, dmu[mt], 0, 0, 0);
            ds2[mt] = __builtin_amdgcn_mfma_f32_16x16x32_bf16(sqf[mt][0], onesf, z4, 0, 0, 0);
            ds2[mt] = __builtin_amdgcn_mfma_f32_16x16x32_bf16(sqf[mt][1], onesf, ds2[mt], 0, 0, 0);
        }
        if (l15 == 0) {
            #pragma unroll
            for (int mt = 0; mt < 2; mt++)
                #pragma unroll
                for (int r = 0; r < 4; r++) {
                    int v = mt * 16 + quad * 4 + r;
                    float mu = dmu[mt][r];
                    float var = ds2[mt][r] - mu * mu;
                    mus[v] = mu;
                    rss[v] = rsqrtf(var + EPSV);
                }
        }
    }
    LGKM0();

    // ---- normalize in-register -> yn A-frags ----
    bf16x8 yna[2][2];
    {
        float muv[2] = {mus[l15], mus[16 + l15]};
        float rsv[2] = {rss[l15], rss[16 + l15]};
        #pragma unroll
        for (int ks = 0; ks < 2; ks++) {
            f32x4 ga = *(const f32x4*)&ln_g[ks * 32 + quad * 8];
            f32x4 gb = *(const f32x4*)&ln_g[ks * 32 + quad * 8 + 4];
            f32x4 ba = *(const f32x4*)&ln_b[ks * 32 + quad * 8];
            f32x4 bb = *(const f32x4*)&ln_b[ks * 32 + quad * 8 + 4];
            #pragma unroll
            for (int mt = 0; mt < 2; mt++) {
                float yv[8];
                #pragma unroll
                for (int j = 0; j < 8; j++) {
                    float g = (j < 4) ? ga[j] : gb[j - 4];
                    float bt = (j < 4) ? ba[j] : bb[j - 4];
                    yv[j] = (xf[mt][ks][j] - muv[mt]) * rsv[mt] * g + bt;
                }
                i32x4 p;
                #pragma unroll
                for (int q = 0; q < 4; q++) p[q] = pack2(yv[2 * q], yv[2 * q + 1]);
                yna[mt][ks] = __builtin_bit_cast(bf16x8, p);
            }
        }
    }

    // ---- accumulators ----
    f32x4 acc[2][4];
    #pragma unroll
    for (int mt = 0; mt < 2; mt++)
        #pragma unroll
        for (int nt = 0; nt < 4; nt++)
            acc[mt][nt] = (f32x4){0.f, 0.f, 0.f, 0.f};

    const f32x4 z4 = {0.f, 0.f, 0.f, 0.f};
    const bf16x8 z8 = {0, 0, 0, 0, 0, 0, 0, 0};

    // per-lane swizzled-address constants (loop-invariant)
    const int sw4 = (l15 >> 2) & 3;                         // row-swizzle for rows l15/16+l15 and o=nt*16+l15
    const int blkA = ((r32 >> 3) ^ hi) << 4;
    unsigned char* gwA = ghb + hi * 256 + (r32 & 7) * 2 + blkA;         // dots write, (r>>2)&1==0
    unsigned char* gwB = ghb + hi * 256 + (r32 & 7) * 2 + (blkA ^ 32);  // dots write, (r>>2)&1==1
    unsigned char* w0p = fwb + ((((quad >> 1) ^ sw4)) << 4) + (quad & 1) * 8;       // FW cols quad*4
    unsigned char* w1p = fwb + (((((quad >> 1) ^ sw4)) ^ 2) << 4) + (quad & 1) * 8; // FW cols 16+quad*4
    unsigned char* brp = fwb + l15 * 64 + ((quad ^ sw4) << 4);                      // FW B-frag read

    // ---- head-pair loop ----
    for (int hp = 0; hp < 4; hp++) {
        // qk tiles: q-tile nt=hp (SCALE*log2e folded), k-tile nt=4+hp
        #pragma unroll
        for (int tsel = 0; tsel < 2; tsel++) {
            int nt = tsel ? (4 + hp) : hp;
            bf16x8 b0 = *(const bf16x8*)&wqk[(nt * 2 + 0) * 512 + lane * 8];
            bf16x8 b1 = *(const bf16x8*)&wqk[(nt * 2 + 1) * 512 + lane * 8];
            float bias = b_qk[(tsel ? 64 : 0) + hp * 16 + l15];
            unsigned short* buf = tsel ? kbuf : qbuf;
            #pragma unroll
            for (int mt = 0; mt < 2; mt++) {
                f32x4 d = __builtin_amdgcn_mfma_f32_16x16x32_bf16(yna[mt][0], b0, z4, 0, 0, 0);
                d = __builtin_amdgcn_mfma_f32_16x16x32_bf16(yna[mt][1], b1, d, 0, 0, 0);
                #pragma unroll
                for (int r = 0; r < 4; r++) {
                    int u = mt * 16 + quad * 4 + r;
                    if (u < 25) {
                        float val = d[r] + bias;
                        if (!tsel) val *= SCALE_L2E;
                        buf[u * 24 + l15] = bfh(val);
                    }
                }
            }
        }
        LGKM0();

        // dots: per head one 32x32x16 MFMA (K=8 real + 8 zero); swizzled Gh writes
        #pragma unroll
        for (int hh = 0; hh < 2; hh++) {
            bf16x8 aq = z8, bk = z8;
            if (hi == 0) {
                aq = *(const bf16x8*)&qbuf[r32 * 24 + hh * 8];
                bk = *(const bf16x8*)&kbuf[r32 * 24 + hh * 8];
            }
            f32x16 dd = {0.f,0.f,0.f,0.f,0.f,0.f,0.f,0.f,0.f,0.f,0.f,0.f,0.f,0.f,0.f,0.f};
            dd = __builtin_amdgcn_mfma_f32_32x32x16_bf16(aq, bk, dd, 0, 0, 0);
            #pragma unroll
            for (int r = 0; r < 16; r++) {
                int ub = (r & 3) + 8 * (r >> 2);
                if (ub + 4 * hi < 25) {
                    unsigned char* p = (((r >> 2) & 1) ? gwB : gwA) + hh * 2048 + ub * 64;
                    *(unsigned short*)p = bfh(dd[r]);
                }
            }
        }
        LGKM0();

        // softmax * topo (50 active lanes: 2 heads x 25 rows), in-place, pad cols zeroed
        {
            int smh = lane >> 5, su = lane & 31;
            if (su < 25) {
                unsigned char* rowb = ghb + smh * 2048 + su * 64;
                int sz = ((su >> 2) & 3) << 4;
                i32x4 ra = *(const i32x4*)(rowb + (sz ^ 0));
                i32x4 rb = *(const i32x4*)(rowb + (sz ^ 16));
                i32x4 rc = *(const i32x4*)(rowb + (sz ^ 32));
                float f[25];
                #pragma unroll
                for (int w = 0; w < 4; w++) {
                    f[2 * w]      = __builtin_bit_cast(float, (unsigned)ra[w] << 16);
                    f[2 * w + 1]  = __builtin_bit_cast(float, (unsigned)ra[w] & 0xFFFF0000u);
                    f[8 + 2 * w]  = __builtin_bit_cast(float, (unsigned)rb[w] << 16);
                    f[9 + 2 * w]  = __builtin_bit_cast(float, (unsigned)rb[w] & 0xFFFF0000u);
                    f[16 + 2 * w] = __builtin_bit_cast(float, (unsigned)rc[w] << 16);
                    f[17 + 2 * w] = __builtin_bit_cast(float, (unsigned)rc[w] & 0xFFFF0000u);
                }
                f[24] = bf2f(*(const unsigned short*)(rowb + (sz ^ 48)));
                // tree max
                float g12[12];
                #pragma unroll
                for (int i2 = 0; i2 < 12; i2++) g12[i2] = fmaxf(f[i2], f[i2 + 12]);
                #pragma unroll
                for (int i2 = 0; i2 < 6; i2++) g12[i2] = fmaxf(g12[i2], g12[i2 + 6]);
                float m = fmaxf(fmaxf(fmaxf(g12[0], g12[1]), fmaxf(g12[2], g12[3])),
                                fmaxf(fmaxf(g12[4], g12[5]), f[24]));
                // exp2 (log2e pre-folded into q) + 4-way sum
                float s0 = 0.f, s1 = 0.f, s2 = 0.f, s3 = 0.f;
                #pragma unroll
                for (int v = 0; v < 24; v += 4) {
                    f[v]     = __builtin_amdgcn_exp2f(f[v] - m);     s0 += f[v];
                    f[v + 1] = __builtin_amdgcn_exp2f(f[v + 1] - m); s1 += f[v + 1];
                    f[v + 2] = __builtin_amdgcn_exp2f(f[v + 2] - m); s2 += f[v + 2];
                    f[v + 3] = __builtin_amdgcn_exp2f(f[v + 3] - m); s3 += f[v + 3];
                }
                f[24] = __builtin_amdgcn_exp2f(f[24] - m);
                float inv = __builtin_amdgcn_rcpf(((s0 + s1) + (s2 + s3)) + f[24]);
                const float* tp = topo + (hp * 2 + smh) * 625 + su * 25;
                #pragma unroll
                for (int v = 0; v < 25; v++) f[v] = f[v] * inv * tp[v];
                int d[12];
                #pragma unroll
                for (int p = 0; p < 12; p++) d[p] = pack2(f[2 * p], f[2 * p + 1]);
                *(i32x4*)(rowb + (sz ^ 0))  = (i32x4){d[0], d[1], d[2], d[3]};
                *(i32x4*)(rowb + (sz ^ 16)) = (i32x4){d[4], d[5], d[6], d[7]};
                *(i32x4*)(rowb + (sz ^ 32)) = (i32x4){d[8], d[9], d[10], d[11]};
                *(i32x4*)(rowb + (sz ^ 48)) = (i32x4){pack2(f[24], 0.f), 0, 0, 0};
            }
        }
        LGKM0();

        // per head: FW_h = feat @ W2ᵀ_h (swizzled FWT), then acc += G_h @ FW_h
        #pragma unroll
        for (int hh = 0; hh < 2; hh++) {
            int h = hp * 2 + hh;
            #pragma unroll
            for (int nt = 0; nt < 4; nt++) {
                bf16x8 w0 = *(const bf16x8*)&w2f[((h * 4 + nt) * 2 + 0) * 512 + lane * 8];
                bf16x8 w1 = *(const bf16x8*)&w2f[((h * 4 + nt) * 2 + 1) * 512 + lane * 8];
                f32x4 dw0 = __builtin_amdgcn_mfma_f32_16x16x32_bf16(xa[0][0], w0, z4, 0, 0, 0);
                dw0 = __builtin_amdgcn_mfma_f32_16x16x32_bf16(xa[0][1], w1, dw0, 0, 0, 0);
                f32x4 dw1 = __builtin_amdgcn_mfma_f32_16x16x32_bf16(xa[1][0], w0, z4, 0, 0, 0);
                dw1 = __builtin_amdgcn_mfma_f32_16x16x32_bf16(xa[1][1], w1, dw1, 0, 0, 0);
                i32x2 q0 = {pack2(dw0[0], dw0[1]), pack2(dw0[2], dw0[3])};
                i32x2 q1 = {pack2(dw1[0], dw1[1]), pack2(dw1[2], dw1[3])};
                *(i32x2*)(w0p + nt * 1024 + l15 * 64) = q0;
                *(i32x2*)(w1p + nt * 1024 + l15 * 64) = q1;
            }
            LGKM0();
            unsigned char* agp = ghb + hh * 2048 + l15 * 64 + ((quad ^ sw4) << 4);
            bf16x8 ag0 = *(const bf16x8*)agp;
            bf16x8 ag1 = *(const bf16x8*)(agp + 1024);
            #pragma unroll
            for (int nt = 0; nt < 4; nt++) {
                bf16x8 br = *(const bf16x8*)(brp + nt * 1024);
                acc[0][nt] = __builtin_amdgcn_mfma_f32_16x16x32_bf16(ag0, br, acc[0][nt], 0, 0, 0);
                acc[1][nt] = __builtin_amdgcn_mfma_f32_16x16x32_bf16(ag1, br, acc[1][nt], 0, 0, 0);
            }
        }
    }

    // ---- epilogue: BN + residual + ReLU, direct global store ----
    #pragma unroll
    for (int nt = 0; nt < 4; nt++) {
        int o = nt * 16 + l15;
        float gA = bnA[o], gB = bnB[o];
        #pragma unroll
        for (int mt = 0; mt < 2; mt++) {
            int ub = mt * 16 + quad * 4;
            #pragma unroll
            for (int r = 0; r < 4; r++) {
                int u = ub + r;
                if (u < 25) {
                    float val = acc[mt][nt][r] * gA + gB + xg[o * 6400 + u];
                    og[o * 6400 + u] = fmaxf(val, 0.f);
                }
            }
        }
    }
}

extern "C" void kernel_launch(void* const* d_in, const int* in_sizes, int n_in,
                              void* d_out, int out_size, void* d_ws, size_t ws_size,
                              hipStream_t stream) {
    const float* x      = (const float*)d_in[0];
    const float* ln_g   = (const float*)d_in[1];
    const float* ln_b   = (const float*)d_in[2];
    const float* w_qk   = (const float*)d_in[3];
    const float* b_qk   = (const float*)d_in[4];
    const float* topo   = (const float*)d_in[5];
    const float* conv_w = (const float*)d_in[6];
    const float* conv_b = (const float*)d_in[7];
    const float* bn_g   = (const float*)d_in[8];
    const float* bn_b   = (const float*)d_in[9];
    const float* bn_m   = (const float*)d_in[10];
    const float* bn_v   = (const float*)d_in[11];
    float* outp = (float*)d_out;
    unsigned short* wsp = (unsigned short*)d_ws;

    hipLaunchKernelGGL(prep_kernel, dim3(161), dim3(256), 0, stream,
                       w_qk, conv_w, conv_b, bn_g, bn_b, bn_m, bn_v, wsp);
    hipLaunchKernelGGL(sagc_kernel, dim3(2048), dim3(256), 0, stream,
                       x, ln_g, ln_b, b_qk, topo, (const unsigned short*)wsp, outp);
}

// Round 2
// 199.133 us; speedup vs baseline: 1.3253x; 1.3253x over previous
//
#include <hip/hip_runtime.h>
#include <math.h>

#define SCALE_L2E 0.51006972157f   // (1/sqrt(8)) * log2(e) -- softmax done in exp2 domain
#define EPSV 1e-5f

typedef __attribute__((ext_vector_type(8))) short bf16x8;
typedef __attribute__((ext_vector_type(4))) float f32x4;
typedef __attribute__((ext_vector_type(16))) float f32x16;
typedef __attribute__((ext_vector_type(4))) int i32x4;
typedef __attribute__((ext_vector_type(2))) int i32x2;

static __device__ __forceinline__ unsigned short bfh(float f) {
    return (unsigned short)(__builtin_bit_cast(unsigned int, f) >> 16);
}
static __device__ __forceinline__ float bf2f(unsigned short s) {
    return __builtin_bit_cast(float, (unsigned int)s << 16);
}
static __device__ __forceinline__ int pack2(float lo, float hi) {
    return __builtin_amdgcn_perm(__builtin_bit_cast(unsigned int, hi),
                                 __builtin_bit_cast(unsigned int, lo), 0x07060302u);
}
#define LGKM0() __asm__ __volatile__("s_waitcnt lgkmcnt(0)" ::: "memory")

// ws layout: [0,8192) ushort wqk B-frags; [8192,40960) ushort W2ᵀ B-frags;
//            byte 81920: float bnA[64], bnB[64]
__global__ void prep_kernel(const float* __restrict__ w_qk,
                            const float* __restrict__ conv_w,
                            const float* __restrict__ conv_b,
                            const float* __restrict__ bn_g, const float* __restrict__ bn_b,
                            const float* __restrict__ bn_m, const float* __restrict__ bn_v,
                            unsigned short* __restrict__ ws) {
    int i = blockIdx.x * 256 + threadIdx.x;
    if (i < 8192) {
        // qk B-frag: frag(nt,ks): val = w_qk[k][n], k=ks*32+(l>>4)*8+j, n=nt*16+(l&15)
        int f = i >> 9, rem = i & 511, l = rem >> 3, j = rem & 7;
        int nt = f >> 1, ks = f & 1;
        int k = ks * 32 + (l >> 4) * 8 + j;
        int nn = nt * 16 + (l & 15);
        ws[i] = bfh(w_qk[k * 128 + nn]);
    } else if (i < 40960) {
        // W2ᵀ B-frag: frag(h,nt,ks): val = conv_w[h][o][c], c=ks*32+(l>>4)*8+j, o=nt*16+(l&15)
        int i2 = i - 8192;
        int g = i2 >> 9, rem = i2 & 511, l = rem >> 3, j = rem & 7;
        int h = g >> 3, nt = (g >> 1) & 3, ks = g & 1;
        int c = ks * 32 + (l >> 4) * 8 + j;
        int o = nt * 16 + (l & 15);
        ws[i] = bfh(conv_w[h * 4096 + o * 64 + c]);
    } else if (i < 41024) {
        int o = i - 40960;
        float gv = bn_g[o] * rsqrtf(bn_v[o] + EPSV);
        float bb = bn_b[o] - bn_m[o] * gv;
        float cb = 0.f;
        for (int h = 0; h < 8; h++) cb += conv_b[h * 64 + o];
        float* wsf = (float*)(ws + 40960);
        wsf[o] = gv;
        wsf[64 + o] = bb + cb * gv;
    }
}

// One WAVE per (n,t) tile; 4 waves/block; NO __syncthreads (all LDS is wave-private).
// Per-wave LDS 8192 B (block 32768 B -> LDS permits 5 blocks/CU):
//   region A [0,4096):   qbuf[32][24]@0 + kbuf[32][24]@1536  (qk->dots)
//                        then FWT swizzled [64 rows][64 B]   (per-hh FW staging)
//   region B [4096,8192): mus[32]/rss[32] (transient) then Gh swizzled [2][32 rows][64 B]
// Swizzle: 16B storage block = logical_block ^ ((row>>2)&3); all accesses 16B/8B aligned.
// launch_bounds(256,4): 128-VGPR cap. (256,5) forced VGPR=48 -> massive scratch
// spill (FETCH 57->148 MB, WRITE 60->208 MB, dur 98->174 us). Do NOT tighten.
__global__ __launch_bounds__(256, 4)
void sagc_kernel(const float* __restrict__ x,
                 const float* __restrict__ ln_g, const float* __restrict__ ln_b,
                 const float* __restrict__ b_qk,
                 const float* __restrict__ topo,
                 const unsigned short* __restrict__ ws,
                 float* __restrict__ out)
{
    __shared__ __align__(16) unsigned char smem[32768];
    const int tid = threadIdx.x;
    const int lane = tid & 63, wv = tid >> 6;
    const int l15 = lane & 15, quad = lane >> 4;
    const int r32 = lane & 31, hi = lane >> 5;

    unsigned char* my = smem + wv * 8192;
    unsigned short* qbuf = (unsigned short*)my;            // [32][24] u16
    unsigned short* kbuf = (unsigned short*)(my + 1536);   // [32][24] u16
    unsigned char*  fwb  = my;                             // FWT swizzled, 4096 B
    unsigned char*  ghb  = my + 4096;                      // Gh swizzled, 2 x 2048 B
    float*          mus  = (float*)(my + 4096);            // transient (pre-loop only)
    float*          rss  = mus + 32;

    const unsigned short* wqk = ws;
    const unsigned short* w2f = ws + 8192;
    const float* bnA = (const float*)(ws + 40960);
    const float* bnB = bnA + 64;

    const int tile = blockIdx.x * 4 + wv;
    const int n = tile >> 8, t = tile & 255;
    const float* xg = x + (size_t)n * 409600 + (size_t)t * 25;   // + c*6400 + v
    float* og = out + (size_t)n * 409600 + (size_t)t * 25;

    // ---- direct-register x load (no LDS staging): xf[mt][ks][j] = x[c][v], 0 at v>=25 ----
    float xf[2][2][8];
    #pragma unroll
    for (int mt = 0; mt < 2; mt++) {
        const int v = mt * 16 + l15;
        const bool ok = (v < 25);
        const float* xc = xg + v;
        #pragma unroll
        for (int ks = 0; ks < 2; ks++)
            #pragma unroll
            for (int j = 0; j < 8; j++) {
                int c = ks * 32 + quad * 8 + j;
                xf[mt][ks][j] = ok ? xc[c * 6400] : 0.f;
            }
    }

    // ---- pack x A-frags + squares ----
    bf16x8 xa[2][2], sqf[2][2];
    #pragma unroll
    for (int mt = 0; mt < 2; mt++)
        #pragma unroll
        for (int ks = 0; ks < 2; ks++) {
            i32x4 pa, ps;
            #pragma unroll
            for (int q = 0; q < 4; q++) {
                float a = xf[mt][ks][2 * q], b = xf[mt][ks][2 * q + 1];
                pa[q] = pack2(a, b);
                ps[q] = pack2(a * a, b * b);
            }
            xa[mt][ks]  = __builtin_bit_cast(bf16x8, pa);
            sqf[mt][ks] = __builtin_bit_cast(bf16x8, ps);
        }

    // ---- LN stats via MFMA (B = ones * 1/64) ----
    {
        i32x4 ones_i = {0x3C803C80, 0x3C803C80, 0x3C803C80, 0x3C803C80};
        bf16x8 onesf = __builtin_bit_cast(bf16x8, ones_i);
        f32x4 z4 = {0.f, 0.f, 0.f, 0.f};
        f32x4 dmu[2], ds2[2];
        #pragma unroll
        for (int mt = 0; mt < 2; mt++) {
            dmu[mt] = __builtin_amdgcn_mfma_f32_16x16x32_bf16(xa[mt][0], onesf, z4, 0, 0, 0);
            dmu[mt] = __builtin_amdgcn_mfma_f32_16x16x32_bf16(xa[mt][1], onesf, dmu[mt], 0, 0, 0);
            ds2[mt] = __builtin_amdgcn_mfma_f32_16x16x32_bf16(sqf[mt][0], onesf, z4, 0, 0, 0);
            ds2[mt] = __builtin_amdgcn_mfma_f32_16x16x32_bf16(sqf[mt][1], onesf, ds2[mt], 0, 0, 0);
        }
        if (l15 == 0) {
            #pragma unroll
            for (int mt = 0; mt < 2; mt++)
                #pragma unroll
                for (int r = 0; r < 4; r++) {
                    int v = mt * 16 + quad * 4 + r;
                    float mu = dmu[mt][r];
                    float var = ds2[mt][r] - mu * mu;
                    mus[v] = mu;
                    rss[v] = rsqrtf(var + EPSV);
                }
        }
    }
    LGKM0();

    // ---- normalize in-register -> yn A-frags ----
    bf16x8 yna[2][2];
    {
        float muv[2] = {mus[l15], mus[16 + l15]};
        float rsv[2] = {rss[l15], rss[16 + l15]};
        #pragma unroll
        for (int ks = 0; ks < 2; ks++) {
            f32x4 ga = *(const f32x4*)&ln_g[ks * 32 + quad * 8];
            f32x4 gb = *(const f32x4*)&ln_g[ks * 32 + quad * 8 + 4];
            f32x4 ba = *(const f32x4*)&ln_b[ks * 32 + quad * 8];
            f32x4 bb = *(const f32x4*)&ln_b[ks * 32 + quad * 8 + 4];
            #pragma unroll
            for (int mt = 0; mt < 2; mt++) {
                float yv[8];
                #pragma unroll
                for (int j = 0; j < 8; j++) {
                    float g = (j < 4) ? ga[j] : gb[j - 4];
                    float bt = (j < 4) ? ba[j] : bb[j - 4];
                    yv[j] = (xf[mt][ks][j] - muv[mt]) * rsv[mt] * g + bt;
                }
                i32x4 p;
                #pragma unroll
                for (int q = 0; q < 4; q++) p[q] = pack2(yv[2 * q], yv[2 * q + 1]);
                yna[mt][ks] = __builtin_bit_cast(bf16x8, p);
            }
        }
    }

    // ---- accumulators ----
    f32x4 acc[2][4];
    #pragma unroll
    for (int mt = 0; mt < 2; mt++)
        #pragma unroll
        for (int nt = 0; nt < 4; nt++)
            acc[mt][nt] = (f32x4){0.f, 0.f, 0.f, 0.f};

    const f32x4 z4 = {0.f, 0.f, 0.f, 0.f};
    const bf16x8 z8 = {0, 0, 0, 0, 0, 0, 0, 0};

    // per-lane swizzled-address constants (loop-invariant)
    const int sw4 = (l15 >> 2) & 3;                         // row-swizzle for rows l15/16+l15 and o=nt*16+l15
    const int blkA = ((r32 >> 3) ^ hi) << 4;
    unsigned char* gwA = ghb + hi * 256 + (r32 & 7) * 2 + blkA;         // dots write, (r>>2)&1==0
    unsigned char* gwB = ghb + hi * 256 + (r32 & 7) * 2 + (blkA ^ 32);  // dots write, (r>>2)&1==1
    unsigned char* w0p = fwb + ((((quad >> 1) ^ sw4)) << 4) + (quad & 1) * 8;       // FW cols quad*4
    unsigned char* w1p = fwb + (((((quad >> 1) ^ sw4)) ^ 2) << 4) + (quad & 1) * 8; // FW cols 16+quad*4
    unsigned char* brp = fwb + l15 * 64 + ((quad ^ sw4) << 4);                      // FW B-frag read

    // ---- head-pair loop ----
    for (int hp = 0; hp < 4; hp++) {
        // qk tiles: q-tile nt=hp (SCALE*log2e folded), k-tile nt=4+hp
        #pragma unroll
        for (int tsel = 0; tsel < 2; tsel++) {
            int nt = tsel ? (4 + hp) : hp;
            bf16x8 b0 = *(const bf16x8*)&wqk[(nt * 2 + 0) * 512 + lane * 8];
            bf16x8 b1 = *(const bf16x8*)&wqk[(nt * 2 + 1) * 512 + lane * 8];
            float bias = b_qk[(tsel ? 64 : 0) + hp * 16 + l15];
            unsigned short* buf = tsel ? kbuf : qbuf;
            #pragma unroll
            for (int mt = 0; mt < 2; mt++) {
                f32x4 d = __builtin_amdgcn_mfma_f32_16x16x32_bf16(yna[mt][0], b0, z4, 0, 0, 0);
                d = __builtin_amdgcn_mfma_f32_16x16x32_bf16(yna[mt][1], b1, d, 0, 0, 0);
                #pragma unroll
                for (int r = 0; r < 4; r++) {
                    int u = mt * 16 + quad * 4 + r;
                    if (u < 25) {
                        float val = d[r] + bias;
                        if (!tsel) val *= SCALE_L2E;
                        buf[u * 24 + l15] = bfh(val);
                    }
                }
            }
        }
        LGKM0();

        // dots: per head one 32x32x16 MFMA (K=8 real + 8 zero); swizzled Gh writes
        #pragma unroll
        for (int hh = 0; hh < 2; hh++) {
            bf16x8 aq = z8, bk = z8;
            if (hi == 0) {
                aq = *(const bf16x8*)&qbuf[r32 * 24 + hh * 8];
                bk = *(const bf16x8*)&kbuf[r32 * 24 + hh * 8];
            }
            f32x16 dd = {0.f,0.f,0.f,0.f,0.f,0.f,0.f,0.f,0.f,0.f,0.f,0.f,0.f,0.f,0.f,0.f};
            dd = __builtin_amdgcn_mfma_f32_32x32x16_bf16(aq, bk, dd, 0, 0, 0);
            #pragma unroll
            for (int r = 0; r < 16; r++) {
                int ub = (r & 3) + 8 * (r >> 2);
                if (ub + 4 * hi < 25) {
                    unsigned char* p = (((r >> 2) & 1) ? gwB : gwA) + hh * 2048 + ub * 64;
                    *(unsigned short*)p = bfh(dd[r]);
                }
            }
        }
        LGKM0();

        // softmax * topo (50 active lanes: 2 heads x 25 rows), in-place, pad cols zeroed
        {
            int smh = lane >> 5, su = lane & 31;
            if (su < 25) {
                unsigned char* rowb = ghb + smh * 2048 + su * 64;
                int sz = ((su >> 2) & 3) << 4;
                i32x4 ra = *(const i32x4*)(rowb + (sz ^ 0));
                i32x4 rb = *(const i32x4*)(rowb + (sz ^ 16));
                i32x4 rc = *(const i32x4*)(rowb + (sz ^ 32));
                float f[25];
                #pragma unroll
                for (int w = 0; w < 4; w++) {
                    f[2 * w]      = __builtin_bit_cast(float, (unsigned)ra[w] << 16);
                    f[2 * w + 1]  = __builtin_bit_cast(float, (unsigned)ra[w] & 0xFFFF0000u);
                    f[8 + 2 * w]  = __builtin_bit_cast(float, (unsigned)rb[w] << 16);
                    f[9 + 2 * w]  = __builtin_bit_cast(float, (unsigned)rb[w] & 0xFFFF0000u);
                    f[16 + 2 * w] = __builtin_bit_cast(float, (unsigned)rc[w] << 16);
                    f[17 + 2 * w] = __builtin_bit_cast(float, (unsigned)rc[w] & 0xFFFF0000u);
                }
                f[24] = bf2f(*(const unsigned short*)(rowb + (sz ^ 48)));
                // tree max
                float g12[12];
                #pragma unroll
                for (int i2 = 0; i2 < 12; i2++) g12[i2] = fmaxf(f[i2], f[i2 + 12]);
                #pragma unroll
                for (int i2 = 0; i2 < 6; i2++) g12[i2] = fmaxf(g12[i2], g12[i2 + 6]);
                float m = fmaxf(fmaxf(fmaxf(g12[0], g12[1]), fmaxf(g12[2], g12[3])),
                                fmaxf(fmaxf(g12[4], g12[5]), f[24]));
                // exp2 (log2e pre-folded into q) + 4-way sum
                float s0 = 0.f, s1 = 0.f, s2 = 0.f, s3 = 0.f;
                #pragma unroll
                for (int v = 0; v < 24; v += 4) {
                    f[v]     = __builtin_amdgcn_exp2f(f[v] - m);     s0 += f[v];
                    f[v + 1] = __builtin_amdgcn_exp2f(f[v + 1] - m); s1 += f[v + 1];
                    f[v + 2] = __builtin_amdgcn_exp2f(f[v + 2] - m); s2 += f[v + 2];
                    f[v + 3] = __builtin_amdgcn_exp2f(f[v + 3] - m); s3 += f[v + 3];
                }
                f[24] = __builtin_amdgcn_exp2f(f[24] - m);
                float inv = __builtin_amdgcn_rcpf(((s0 + s1) + (s2 + s3)) + f[24]);
                const float* tp = topo + (hp * 2 + smh) * 625 + su * 25;
                #pragma unroll
                for (int v = 0; v < 25; v++) f[v] = f[v] * inv * tp[v];
                int d[12];
                #pragma unroll
                for (int p = 0; p < 12; p++) d[p] = pack2(f[2 * p], f[2 * p + 1]);
                *(i32x4*)(rowb + (sz ^ 0))  = (i32x4){d[0], d[1], d[2], d[3]};
                *(i32x4*)(rowb + (sz ^ 16)) = (i32x4){d[4], d[5], d[6], d[7]};
                *(i32x4*)(rowb + (sz ^ 32)) = (i32x4){d[8], d[9], d[10], d[11]};
                *(i32x4*)(rowb + (sz ^ 48)) = (i32x4){pack2(f[24], 0.f), 0, 0, 0};
            }
        }
        LGKM0();

        // per head: FW_h = feat @ W2ᵀ_h (swizzled FWT), then acc += G_h @ FW_h
        #pragma unroll
        for (int hh = 0; hh < 2; hh++) {
            int h = hp * 2 + hh;
            #pragma unroll
            for (int nt = 0; nt < 4; nt++) {
                bf16x8 w0 = *(const bf16x8*)&w2f[((h * 4 + nt) * 2 + 0) * 512 + lane * 8];
                bf16x8 w1 = *(const bf16x8*)&w2f[((h * 4 + nt) * 2 + 1) * 512 + lane * 8];
                f32x4 dw0 = __builtin_amdgcn_mfma_f32_16x16x32_bf16(xa[0][0], w0, z4, 0, 0, 0);
                dw0 = __builtin_amdgcn_mfma_f32_16x16x32_bf16(xa[0][1], w1, dw0, 0, 0, 0);
                f32x4 dw1 = __builtin_amdgcn_mfma_f32_16x16x32_bf16(xa[1][0], w0, z4, 0, 0, 0);
                dw1 = __builtin_amdgcn_mfma_f32_16x16x32_bf16(xa[1][1], w1, dw1, 0, 0, 0);
                i32x2 q0 = {pack2(dw0[0], dw0[1]), pack2(dw0[2], dw0[3])};
                i32x2 q1 = {pack2(dw1[0], dw1[1]), pack2(dw1[2], dw1[3])};
                *(i32x2*)(w0p + nt * 1024 + l15 * 64) = q0;
                *(i32x2*)(w1p + nt * 1024 + l15 * 64) = q1;
            }
            LGKM0();
            unsigned char* agp = ghb + hh * 2048 + l15 * 64 + ((quad ^ sw4) << 4);
            bf16x8 ag0 = *(const bf16x8*)agp;
            bf16x8 ag1 = *(const bf16x8*)(agp + 1024);
            #pragma unroll
            for (int nt = 0; nt < 4; nt++) {
                bf16x8 br = *(const bf16x8*)(brp + nt * 1024);
                acc[0][nt] = __builtin_amdgcn_mfma_f32_16x16x32_bf16(ag0, br, acc[0][nt], 0, 0, 0);
                acc[1][nt] = __builtin_amdgcn_mfma_f32_16x16x32_bf16(ag1, br, acc[1][nt], 0, 0, 0);
            }
        }
    }

    // ---- epilogue: BN + residual + ReLU, direct global store ----
    #pragma unroll
    for (int nt = 0; nt < 4; nt++) {
        int o = nt * 16 + l15;
        float gA = bnA[o], gB = bnB[o];
        #pragma unroll
        for (int mt = 0; mt < 2; mt++) {
            int ub = mt * 16 + quad * 4;
            #pragma unroll
            for (int r = 0; r < 4; r++) {
                int u = ub + r;
                if (u < 25) {
                    float val = acc[mt][nt][r] * gA + gB + xg[o * 6400 + u];
                    og[o * 6400 + u] = fmaxf(val, 0.f);
                }
            }
        }
    }
}

extern "C" void kernel_launch(void* const* d_in, const int* in_sizes, int n_in,
                              void* d_out, int out_size, void* d_ws, size_t ws_size,
                              hipStream_t stream) {
    const float* x      = (const float*)d_in[0];
    const float* ln_g   = (const float*)d_in[1];
    const float* ln_b   = (const float*)d_in[2];
    const float* w_qk   = (const float*)d_in[3];
    const float* b_qk   = (const float*)d_in[4];
    const float* topo   = (const float*)d_in[5];
    const float* conv_w = (const float*)d_in[6];
    const float* conv_b = (const float*)d_in[7];
    const float* bn_g   = (const float*)d_in[8];
    const float* bn_b   = (const float*)d_in[9];
    const float* bn_m   = (const float*)d_in[10];
    const float* bn_v   = (const float*)d_in[11];
    float* outp = (float*)d_out;
    unsigned short* wsp = (unsigned short*)d_ws;

    hipLaunchKernelGGL(prep_kernel, dim3(161), dim3(256), 0, stream,
                       w_qk, conv_w, conv_b, bn_g, bn_b, bn_m, bn_v, wsp);
    hipLaunchKernelGGL(sagc_kernel, dim3(2048), dim3(256), 0, stream,
                       x, ln_g, ln_b, b_qk, topo, (const unsigned short*)wsp, outp);
}

// Round 3
// 190.909 us; speedup vs baseline: 1.3824x; 1.0431x over previous
//
#include <hip/hip_runtime.h>
#include <math.h>

#define SCALE_L2E 0.51006972157f   // (1/sqrt(8)) * log2(e) -- softmax done in exp2 domain
#define EPSV 1e-5f

typedef __attribute__((ext_vector_type(8))) short bf16x8;
typedef __attribute__((ext_vector_type(4))) float f32x4;
typedef __attribute__((ext_vector_type(16))) float f32x16;
typedef __attribute__((ext_vector_type(4))) int i32x4;
typedef __attribute__((ext_vector_type(2))) int i32x2;

static __device__ __forceinline__ unsigned short bfh(float f) {
    return (unsigned short)(__builtin_bit_cast(unsigned int, f) >> 16);
}
static __device__ __forceinline__ float bf2f(unsigned short s) {
    return __builtin_bit_cast(float, (unsigned int)s << 16);
}
static __device__ __forceinline__ int pack2(float lo, float hi) {
    return __builtin_amdgcn_perm(__builtin_bit_cast(unsigned int, hi),
                                 __builtin_bit_cast(unsigned int, lo), 0x07060302u);
}
#define LGKM0() __asm__ __volatile__("s_waitcnt lgkmcnt(0)" ::: "memory")

// ws layout: [0,8192) ushort wqk B-frags; [8192,40960) ushort W2ᵀ B-frags;
//            byte 81920: float bnA[64], bnB[64]
__global__ void prep_kernel(const float* __restrict__ w_qk,
                            const float* __restrict__ conv_w,
                            const float* __restrict__ conv_b,
                            const float* __restrict__ bn_g, const float* __restrict__ bn_b,
                            const float* __restrict__ bn_m, const float* __restrict__ bn_v,
                            unsigned short* __restrict__ ws) {
    int i = blockIdx.x * 256 + threadIdx.x;
    if (i < 8192) {
        // qk B-frag: frag(nt,ks): val = w_qk[k][n], k=ks*32+(l>>4)*8+j, n=nt*16+(l&15)
        int f = i >> 9, rem = i & 511, l = rem >> 3, j = rem & 7;
        int nt = f >> 1, ks = f & 1;
        int k = ks * 32 + (l >> 4) * 8 + j;
        int nn = nt * 16 + (l & 15);
        ws[i] = bfh(w_qk[k * 128 + nn]);
    } else if (i < 40960) {
        // W2ᵀ B-frag: frag(h,nt,ks): val = conv_w[h][o][c], c=ks*32+(l>>4)*8+j, o=nt*16+(l&15)
        int i2 = i - 8192;
        int g = i2 >> 9, rem = i2 & 511, l = rem >> 3, j = rem & 7;
        int h = g >> 3, nt = (g >> 1) & 3, ks = g & 1;
        int c = ks * 32 + (l >> 4) * 8 + j;
        int o = nt * 16 + (l & 15);
        ws[i] = bfh(conv_w[h * 4096 + o * 64 + c]);
    } else if (i < 41024) {
        int o = i - 40960;
        float gv = bn_g[o] * rsqrtf(bn_v[o] + EPSV);
        float bb = bn_b[o] - bn_m[o] * gv;
        float cb = 0.f;
        for (int h = 0; h < 8; h++) cb += conv_b[h * 64 + o];
        float* wsf = (float*)(ws + 40960);
        wsf[o] = gv;
        wsf[64 + o] = bb + cb * gv;
    }
}

// One WAVE per (n,t) tile; 4 waves/block; NO __syncthreads (all LDS is wave-private).
// Per-wave LDS 8192 B (block 32768 B -> LDS cap 5 blocks/CU = 20 waves):
//   region A [0,4096):   qbuf[32][24]@0 + kbuf[32][24]@1536  (qk->dots)
//                        then FWT swizzled [64 rows][64 B]   (per-hh FW staging)
//   region B [4096,8192): mus[32]/rss[32] (transient) then Gh swizzled [2][32 rows][64 B]
// Swizzle: 16B storage block = logical_block ^ ((row>>2)&3); all accesses 16B/8B aligned.
// VGPR cap vs spill (MEASURED):
//   (256,3) -> cap 80:  no spill (r0: FETCH 57 MB ~= ideal)
//   (256,4) -> cap 64:  spill    (r2: FETCH 78 MB, WRITE 88 MB, +50 MB scratch)
//   (256,5) -> cap 48:  heavy spill (r1: FETCH 148, WRITE 208, dur 174us)
// True peak live ~80-100 (xa16+yna16+acc32 persistent + softmax f[25]+d[12]).
// 80 VGPR still allows 16 waves/CU (occupancy steps at 64/128/256). Do NOT tighten.
__global__ __launch_bounds__(256, 3)
void sagc_kernel(const float* __restrict__ x,
                 const float* __restrict__ ln_g, const float* __restrict__ ln_b,
                 const float* __restrict__ b_qk,
                 const float* __restrict__ topo,
                 const unsigned short* __restrict__ ws,
                 float* __restrict__ out)
{
    __shared__ __align__(16) unsigned char smem[32768];
    const int tid = threadIdx.x;
    const int lane = tid & 63, wv = tid >> 6;
    const int l15 = lane & 15, quad = lane >> 4;
    const int r32 = lane & 31, hi = lane >> 5;

    unsigned char* my = smem + wv * 8192;
    unsigned short* qbuf = (unsigned short*)my;            // [32][24] u16
    unsigned short* kbuf = (unsigned short*)(my + 1536);   // [32][24] u16
    unsigned char*  fwb  = my;                             // FWT swizzled, 4096 B
    unsigned char*  ghb  = my + 4096;                      // Gh swizzled, 2 x 2048 B
    float*          mus  = (float*)(my + 4096);            // transient (pre-loop only)
    float*          rss  = mus + 32;

    const unsigned short* wqk = ws;
    const unsigned short* w2f = ws + 8192;
    const float* bnA = (const float*)(ws + 40960);
    const float* bnB = bnA + 64;

    const int tile = blockIdx.x * 4 + wv;
    const int n = tile >> 8, t = tile & 255;
    const float* xg = x + (size_t)n * 409600 + (size_t)t * 25;   // + c*6400 + v
    float* og = out + (size_t)n * 409600 + (size_t)t * 25;

    // ---- direct-register x load (no LDS staging): xf[mt][ks][j] = x[c][v], 0 at v>=25 ----
    float xf[2][2][8];
    #pragma unroll
    for (int mt = 0; mt < 2; mt++) {
        const int v = mt * 16 + l15;
        const bool ok = (v < 25);
        const float* xc = xg + v;
        #pragma unroll
        for (int ks = 0; ks < 2; ks++)
            #pragma unroll
            for (int j = 0; j < 8; j++) {
                int c = ks * 32 + quad * 8 + j;
                xf[mt][ks][j] = ok ? xc[c * 6400] : 0.f;
            }
    }

    // ---- pack x A-frags + squares ----
    bf16x8 xa[2][2], sqf[2][2];
    #pragma unroll
    for (int mt = 0; mt < 2; mt++)
        #pragma unroll
        for (int ks = 0; ks < 2; ks++) {
            i32x4 pa, ps;
            #pragma unroll
            for (int q = 0; q < 4; q++) {
                float a = xf[mt][ks][2 * q], b = xf[mt][ks][2 * q + 1];
                pa[q] = pack2(a, b);
                ps[q] = pack2(a * a, b * b);
            }
            xa[mt][ks]  = __builtin_bit_cast(bf16x8, pa);
            sqf[mt][ks] = __builtin_bit_cast(bf16x8, ps);
        }

    // ---- LN stats via MFMA (B = ones * 1/64) ----
    {
        i32x4 ones_i = {0x3C803C80, 0x3C803C80, 0x3C803C80, 0x3C803C80};
        bf16x8 onesf = __builtin_bit_cast(bf16x8, ones_i);
        f32x4 z4 = {0.f, 0.f, 0.f, 0.f};
        f32x4 dmu[2], ds2[2];
        #pragma unroll
        for (int mt = 0; mt < 2; mt++) {
            dmu[mt] = __builtin_amdgcn_mfma_f32_16x16x32_bf16(xa[mt][0], onesf, z4, 0, 0, 0);
            dmu[mt] = __builtin_amdgcn_mfma_f32_16x16x32_bf16(xa[mt][1], onesf, dmu[mt], 0, 0, 0);
            ds2[mt] = __builtin_amdgcn_mfma_f32_16x16x32_bf16(sqf[mt][0], onesf, z4, 0, 0, 0);
            ds2[mt] = __builtin_amdgcn_mfma_f32_16x16x32_bf16(sqf[mt][1], onesf, ds2[mt], 0, 0, 0);
        }
        if (l15 == 0) {
            #pragma unroll
            for (int mt = 0; mt < 2; mt++)
                #pragma unroll
                for (int r = 0; r < 4; r++) {
                    int v = mt * 16 + quad * 4 + r;
                    float mu = dmu[mt][r];
                    float var = ds2[mt][r] - mu * mu;
                    mus[v] = mu;
                    rss[v] = rsqrtf(var + EPSV);
                }
        }
    }
    LGKM0();

    // ---- normalize in-register -> yn A-frags ----
    bf16x8 yna[2][2];
    {
        float muv[2] = {mus[l15], mus[16 + l15]};
        float rsv[2] = {rss[l15], rss[16 + l15]};
        #pragma unroll
        for (int ks = 0; ks < 2; ks++) {
            f32x4 ga = *(const f32x4*)&ln_g[ks * 32 + quad * 8];
            f32x4 gb = *(const f32x4*)&ln_g[ks * 32 + quad * 8 + 4];
            f32x4 ba = *(const f32x4*)&ln_b[ks * 32 + quad * 8];
            f32x4 bb = *(const f32x4*)&ln_b[ks * 32 + quad * 8 + 4];
            #pragma unroll
            for (int mt = 0; mt < 2; mt++) {
                float yv[8];
                #pragma unroll
                for (int j = 0; j < 8; j++) {
                    float g = (j < 4) ? ga[j] : gb[j - 4];
                    float bt = (j < 4) ? ba[j] : bb[j - 4];
                    yv[j] = (xf[mt][ks][j] - muv[mt]) * rsv[mt] * g + bt;
                }
                i32x4 p;
                #pragma unroll
                for (int q = 0; q < 4; q++) p[q] = pack2(yv[2 * q], yv[2 * q + 1]);
                yna[mt][ks] = __builtin_bit_cast(bf16x8, p);
            }
        }
    }

    // ---- accumulators ----
    f32x4 acc[2][4];
    #pragma unroll
    for (int mt = 0; mt < 2; mt++)
        #pragma unroll
        for (int nt = 0; nt < 4; nt++)
            acc[mt][nt] = (f32x4){0.f, 0.f, 0.f, 0.f};

    const f32x4 z4 = {0.f, 0.f, 0.f, 0.f};
    const bf16x8 z8 = {0, 0, 0, 0, 0, 0, 0, 0};

    // per-lane swizzled-address constants (loop-invariant)
    const int sw4 = (l15 >> 2) & 3;                         // row-swizzle for rows l15/16+l15 and o=nt*16+l15
    const int blkA = ((r32 >> 3) ^ hi) << 4;
    unsigned char* gwA = ghb + hi * 256 + (r32 & 7) * 2 + blkA;         // dots write, (r>>2)&1==0
    unsigned char* gwB = ghb + hi * 256 + (r32 & 7) * 2 + (blkA ^ 32);  // dots write, (r>>2)&1==1
    unsigned char* w0p = fwb + ((((quad >> 1) ^ sw4)) << 4) + (quad & 1) * 8;       // FW cols quad*4
    unsigned char* w1p = fwb + (((((quad >> 1) ^ sw4)) ^ 2) << 4) + (quad & 1) * 8; // FW cols 16+quad*4
    unsigned char* brp = fwb + l15 * 64 + ((quad ^ sw4) << 4);                      // FW B-frag read

    // ---- head-pair loop ----
    for (int hp = 0; hp < 4; hp++) {
        // qk tiles: q-tile nt=hp (SCALE*log2e folded), k-tile nt=4+hp
        #pragma unroll
        for (int tsel = 0; tsel < 2; tsel++) {
            int nt = tsel ? (4 + hp) : hp;
            bf16x8 b0 = *(const bf16x8*)&wqk[(nt * 2 + 0) * 512 + lane * 8];
            bf16x8 b1 = *(const bf16x8*)&wqk[(nt * 2 + 1) * 512 + lane * 8];
            float bias = b_qk[(tsel ? 64 : 0) + hp * 16 + l15];
            unsigned short* buf = tsel ? kbuf : qbuf;
            #pragma unroll
            for (int mt = 0; mt < 2; mt++) {
                f32x4 d = __builtin_amdgcn_mfma_f32_16x16x32_bf16(yna[mt][0], b0, z4, 0, 0, 0);
                d = __builtin_amdgcn_mfma_f32_16x16x32_bf16(yna[mt][1], b1, d, 0, 0, 0);
                #pragma unroll
                for (int r = 0; r < 4; r++) {
                    int u = mt * 16 + quad * 4 + r;
                    if (u < 25) {
                        float val = d[r] + bias;
                        if (!tsel) val *= SCALE_L2E;
                        buf[u * 24 + l15] = bfh(val);
                    }
                }
            }
        }
        LGKM0();

        // dots: per head one 32x32x16 MFMA (K=8 real + 8 zero); swizzled Gh writes
        #pragma unroll
        for (int hh = 0; hh < 2; hh++) {
            bf16x8 aq = z8, bk = z8;
            if (hi == 0) {
                aq = *(const bf16x8*)&qbuf[r32 * 24 + hh * 8];
                bk = *(const bf16x8*)&kbuf[r32 * 24 + hh * 8];
            }
            f32x16 dd = {0.f,0.f,0.f,0.f,0.f,0.f,0.f,0.f,0.f,0.f,0.f,0.f,0.f,0.f,0.f,0.f};
            dd = __builtin_amdgcn_mfma_f32_32x32x16_bf16(aq, bk, dd, 0, 0, 0);
            #pragma unroll
            for (int r = 0; r < 16; r++) {
                int ub = (r & 3) + 8 * (r >> 2);
                if (ub + 4 * hi < 25) {
                    unsigned char* p = (((r >> 2) & 1) ? gwB : gwA) + hh * 2048 + ub * 64;
                    *(unsigned short*)p = bfh(dd[r]);
                }
            }
        }
        LGKM0();

        // softmax * topo (50 active lanes: 2 heads x 25 rows), in-place, pad cols zeroed
        {
            int smh = lane >> 5, su = lane & 31;
            if (su < 25) {
                unsigned char* rowb = ghb + smh * 2048 + su * 64;
                int sz = ((su >> 2) & 3) << 4;
                i32x4 ra = *(const i32x4*)(rowb + (sz ^ 0));
                i32x4 rb = *(const i32x4*)(rowb + (sz ^ 16));
                i32x4 rc = *(const i32x4*)(rowb + (sz ^ 32));
                float f[25];
                #pragma unroll
                for (int w = 0; w < 4; w++) {
                    f[2 * w]      = __builtin_bit_cast(float, (unsigned)ra[w] << 16);
                    f[2 * w + 1]  = __builtin_bit_cast(float, (unsigned)ra[w] & 0xFFFF0000u);
                    f[8 + 2 * w]  = __builtin_bit_cast(float, (unsigned)rb[w] << 16);
                    f[9 + 2 * w]  = __builtin_bit_cast(float, (unsigned)rb[w] & 0xFFFF0000u);
                    f[16 + 2 * w] = __builtin_bit_cast(float, (unsigned)rc[w] << 16);
                    f[17 + 2 * w] = __builtin_bit_cast(float, (unsigned)rc[w] & 0xFFFF0000u);
                }
                f[24] = bf2f(*(const unsigned short*)(rowb + (sz ^ 48)));
                // tree max
                float g12[12];
                #pragma unroll
                for (int i2 = 0; i2 < 12; i2++) g12[i2] = fmaxf(f[i2], f[i2 + 12]);
                #pragma unroll
                for (int i2 = 0; i2 < 6; i2++) g12[i2] = fmaxf(g12[i2], g12[i2 + 6]);
                float m = fmaxf(fmaxf(fmaxf(g12[0], g12[1]), fmaxf(g12[2], g12[3])),
                                fmaxf(fmaxf(g12[4], g12[5]), f[24]));
                // exp2 (log2e pre-folded into q) + 4-way sum
                float s0 = 0.f, s1 = 0.f, s2 = 0.f, s3 = 0.f;
                #pragma unroll
                for (int v = 0; v < 24; v += 4) {
                    f[v]     = __builtin_amdgcn_exp2f(f[v] - m);     s0 += f[v];
                    f[v + 1] = __builtin_amdgcn_exp2f(f[v + 1] - m); s1 += f[v + 1];
                    f[v + 2] = __builtin_amdgcn_exp2f(f[v + 2] - m); s2 += f[v + 2];
                    f[v + 3] = __builtin_amdgcn_exp2f(f[v + 3] - m); s3 += f[v + 3];
                }
                f[24] = __builtin_amdgcn_exp2f(f[24] - m);
                float inv = __builtin_amdgcn_rcpf(((s0 + s1) + (s2 + s3)) + f[24]);
                const float* tp = topo + (hp * 2 + smh) * 625 + su * 25;
                #pragma unroll
                for (int v = 0; v < 25; v++) f[v] = f[v] * inv * tp[v];
                int d[12];
                #pragma unroll
                for (int p = 0; p < 12; p++) d[p] = pack2(f[2 * p], f[2 * p + 1]);
                *(i32x4*)(rowb + (sz ^ 0))  = (i32x4){d[0], d[1], d[2], d[3]};
                *(i32x4*)(rowb + (sz ^ 16)) = (i32x4){d[4], d[5], d[6], d[7]};
                *(i32x4*)(rowb + (sz ^ 32)) = (i32x4){d[8], d[9], d[10], d[11]};
                *(i32x4*)(rowb + (sz ^ 48)) = (i32x4){pack2(f[24], 0.f), 0, 0, 0};
            }
        }
        LGKM0();

        // per head: FW_h = feat @ W2ᵀ_h (swizzled FWT), then acc += G_h @ FW_h
        #pragma unroll
        for (int hh = 0; hh < 2; hh++) {
            int h = hp * 2 + hh;
            #pragma unroll
            for (int nt = 0; nt < 4; nt++) {
                bf16x8 w0 = *(const bf16x8*)&w2f[((h * 4 + nt) * 2 + 0) * 512 + lane * 8];
                bf16x8 w1 = *(const bf16x8*)&w2f[((h * 4 + nt) * 2 + 1) * 512 + lane * 8];
                f32x4 dw0 = __builtin_amdgcn_mfma_f32_16x16x32_bf16(xa[0][0], w0, z4, 0, 0, 0);
                dw0 = __builtin_amdgcn_mfma_f32_16x16x32_bf16(xa[0][1], w1, dw0, 0, 0, 0);
                f32x4 dw1 = __builtin_amdgcn_mfma_f32_16x16x32_bf16(xa[1][0], w0, z4, 0, 0, 0);
                dw1 = __builtin_amdgcn_mfma_f32_16x16x32_bf16(xa[1][1], w1, dw1, 0, 0, 0);
                i32x2 q0 = {pack2(dw0[0], dw0[1]), pack2(dw0[2], dw0[3])};
                i32x2 q1 = {pack2(dw1[0], dw1[1]), pack2(dw1[2], dw1[3])};
                *(i32x2*)(w0p + nt * 1024 + l15 * 64) = q0;
                *(i32x2*)(w1p + nt * 1024 + l15 * 64) = q1;
            }
            LGKM0();
            unsigned char* agp = ghb + hh * 2048 + l15 * 64 + ((quad ^ sw4) << 4);
            bf16x8 ag0 = *(const bf16x8*)agp;
            bf16x8 ag1 = *(const bf16x8*)(agp + 1024);
            #pragma unroll
            for (int nt = 0; nt < 4; nt++) {
                bf16x8 br = *(const bf16x8*)(brp + nt * 1024);
                acc[0][nt] = __builtin_amdgcn_mfma_f32_16x16x32_bf16(ag0, br, acc[0][nt], 0, 0, 0);
                acc[1][nt] = __builtin_amdgcn_mfma_f32_16x16x32_bf16(ag1, br, acc[1][nt], 0, 0, 0);
            }
        }
    }

    // ---- epilogue: BN + residual + ReLU, direct global store ----
    #pragma unroll
    for (int nt = 0; nt < 4; nt++) {
        int o = nt * 16 + l15;
        float gA = bnA[o], gB = bnB[o];
        #pragma unroll
        for (int mt = 0; mt < 2; mt++) {
            int ub = mt * 16 + quad * 4;
            #pragma unroll
            for (int r = 0; r < 4; r++) {
                int u = ub + r;
                if (u < 25) {
                    float val = acc[mt][nt][r] * gA + gB + xg[o * 6400 + u];
                    og[o * 6400 + u] = fmaxf(val, 0.f);
                }
            }
        }
    }
}

extern "C" void kernel_launch(void* const* d_in, const int* in_sizes, int n_in,
                              void* d_out, int out_size, void* d_ws, size_t ws_size,
                              hipStream_t stream) {
    const float* x      = (const float*)d_in[0];
    const float* ln_g   = (const float*)d_in[1];
    const float* ln_b   = (const float*)d_in[2];
    const float* w_qk   = (const float*)d_in[3];
    const float* b_qk   = (const float*)d_in[4];
    const float* topo   = (const float*)d_in[5];
    const float* conv_w = (const float*)d_in[6];
    const float* conv_b = (const float*)d_in[7];
    const float* bn_g   = (const float*)d_in[8];
    const float* bn_b   = (const float*)d_in[9];
    const float* bn_m   = (const float*)d_in[10];
    const float* bn_v   = (const float*)d_in[11];
    float* outp = (float*)d_out;
    unsigned short* wsp = (unsigned short*)d_ws;

    hipLaunchKernelGGL(prep_kernel, dim3(161), dim3(256), 0, stream,
                       w_qk, conv_w, conv_b, bn_g, bn_b, bn_m, bn_v, wsp);
    hipLaunchKernelGGL(sagc_kernel, dim3(2048), dim3(256), 0, stream,
                       x, ln_g, ln_b, b_qk, topo, (const unsigned short*)wsp, outp);
}

// Round 4
// 185.941 us; speedup vs baseline: 1.4193x; 1.0267x over previous
//
#include <hip/hip_runtime.h>
#include <math.h>

#define SCALE_L2E 0.51006972157f   // (1/sqrt(8)) * log2(e) -- softmax done in exp2 domain
#define EPSV 1e-5f

typedef __attribute__((ext_vector_type(8))) short bf16x8;
typedef __attribute__((ext_vector_type(4))) float f32x4;
typedef __attribute__((ext_vector_type(16))) float f32x16;
typedef __attribute__((ext_vector_type(4))) int i32x4;
typedef __attribute__((ext_vector_type(2))) int i32x2;

static __device__ __forceinline__ unsigned short bfh(float f) {
    return (unsigned short)(__builtin_bit_cast(unsigned int, f) >> 16);
}
static __device__ __forceinline__ float bf2f(unsigned short s) {
    return __builtin_bit_cast(float, (unsigned int)s << 16);
}
static __device__ __forceinline__ int pack2(float lo, float hi) {
    return __builtin_amdgcn_perm(__builtin_bit_cast(unsigned int, hi),
                                 __builtin_bit_cast(unsigned int, lo), 0x07060302u);
}
#define LGKM0() __asm__ __volatile__("s_waitcnt lgkmcnt(0)" ::: "memory")

// ws layout: [0,8192) ushort wqk B-frags; [8192,40960) ushort W2ᵀ B-frags;
//            byte 81920: float bnA[64], bnB[64]
__global__ void prep_kernel(const float* __restrict__ w_qk,
                            const float* __restrict__ conv_w,
                            const float* __restrict__ conv_b,
                            const float* __restrict__ bn_g, const float* __restrict__ bn_b,
                            const float* __restrict__ bn_m, const float* __restrict__ bn_v,
                            unsigned short* __restrict__ ws) {
    int i = blockIdx.x * 256 + threadIdx.x;
    if (i < 8192) {
        // qk B-frag: frag(nt,ks): val = w_qk[k][n], k=ks*32+(l>>4)*8+j, n=nt*16+(l&15)
        int f = i >> 9, rem = i & 511, l = rem >> 3, j = rem & 7;
        int nt = f >> 1, ks = f & 1;
        int k = ks * 32 + (l >> 4) * 8 + j;
        int nn = nt * 16 + (l & 15);
        ws[i] = bfh(w_qk[k * 128 + nn]);
    } else if (i < 40960) {
        // W2ᵀ B-frag: frag(h,nt,ks): val = conv_w[h][o][c], c=ks*32+(l>>4)*8+j, o=nt*16+(l&15)
        int i2 = i - 8192;
        int g = i2 >> 9, rem = i2 & 511, l = rem >> 3, j = rem & 7;
        int h = g >> 3, nt = (g >> 1) & 3, ks = g & 1;
        int c = ks * 32 + (l >> 4) * 8 + j;
        int o = nt * 16 + (l & 15);
        ws[i] = bfh(conv_w[h * 4096 + o * 64 + c]);
    } else if (i < 41024) {
        int o = i - 40960;
        float gv = bn_g[o] * rsqrtf(bn_v[o] + EPSV);
        float bb = bn_b[o] - bn_m[o] * gv;
        float cb = 0.f;
        for (int h = 0; h < 8; h++) cb += conv_b[h * 64 + o];
        float* wsf = (float*)(ws + 40960);
        wsf[o] = gv;
        wsf[64 + o] = bb + cb * gv;
    }
}

// One WAVE per (n,t) tile; 4 waves/block; NO __syncthreads (all LDS is wave-private).
// Per-wave LDS 8192 B (block 32768 B):
//   region A [0,4096):   qbuf[32][24]@0 + kbuf[32][24]@1536  (qk->dots)
//                        then FWT swizzled [64 rows][64 B]   (per-hh FW staging)
//   region B [4096,8192): Gh swizzled [2][32 rows][64 B]
// Swizzle: 16B storage block = logical_block ^ ((row>>2)&3); all accesses 16B/8B aligned.
// VGPR cap vs spill/occupancy (MEASURED r0-r3):
//   cap 48 (256,5): heavy spill, 174us | cap 64 (256,4): spill, 108us, occ 38%
//   cap 80 (256,3): no spill, 99us, occ 27.5% | LDS 53K->32K at cap 80: occ UNCHANGED
//   => occupancy follows the VGPR quantum (steps at 64/128): 80 and 128 give the
//   SAME 4 waves/SIMD. (256,2)=cap 128 is free headroom for prefetch. Do NOT tighten.
__global__ __launch_bounds__(256, 2)
void sagc_kernel(const float* __restrict__ x,
                 const float* __restrict__ ln_g, const float* __restrict__ ln_b,
                 const float* __restrict__ b_qk,
                 const float* __restrict__ topo,
                 const unsigned short* __restrict__ ws,
                 float* __restrict__ out)
{
    __shared__ __align__(16) unsigned char smem[32768];
    const int tid = threadIdx.x;
    const int lane = tid & 63, wv = tid >> 6;
    const int l15 = lane & 15, quad = lane >> 4;
    const int r32 = lane & 31, hi = lane >> 5;

    unsigned char* my = smem + wv * 8192;
    unsigned short* qbuf = (unsigned short*)my;            // [32][24] u16
    unsigned short* kbuf = (unsigned short*)(my + 1536);   // [32][24] u16
    unsigned char*  fwb  = my;                             // FWT swizzled, 4096 B
    unsigned char*  ghb  = my + 4096;                      // Gh swizzled, 2 x 2048 B

    const unsigned short* wqk = ws;
    const unsigned short* w2f = ws + 8192;
    const float* bnA = (const float*)(ws + 40960);
    const float* bnB = bnA + 64;

    const int tile = blockIdx.x * 4 + wv;
    const int n = tile >> 8, t = tile & 255;
    const float* xg = x + (size_t)n * 409600 + (size_t)t * 25;   // + c*6400 + v
    float* og = out + (size_t)n * 409600 + (size_t)t * 25;

    // ---- direct-register x load (no LDS staging): xf[mt][ks][j] = x[c][v], 0 at v>=25 ----
    float xf[2][2][8];
    #pragma unroll
    for (int mt = 0; mt < 2; mt++) {
        const int v = mt * 16 + l15;
        const bool ok = (v < 25);
        const float* xc = xg + v;
        #pragma unroll
        for (int ks = 0; ks < 2; ks++)
            #pragma unroll
            for (int j = 0; j < 8; j++) {
                int c = ks * 32 + quad * 8 + j;
                xf[mt][ks][j] = ok ? xc[c * 6400] : 0.f;
            }
    }

    // ---- pack x A-frags; accumulate per-row sums for LN stats ----
    bf16x8 xa[2][2];
    float sum_[2] = {0.f, 0.f}, ssq_[2] = {0.f, 0.f};
    #pragma unroll
    for (int mt = 0; mt < 2; mt++)
        #pragma unroll
        for (int ks = 0; ks < 2; ks++) {
            i32x4 pa;
            #pragma unroll
            for (int q = 0; q < 4; q++)
                pa[q] = pack2(xf[mt][ks][2 * q], xf[mt][ks][2 * q + 1]);
            xa[mt][ks] = __builtin_bit_cast(bf16x8, pa);
            #pragma unroll
            for (int j = 0; j < 8; j++) {
                float a = xf[mt][ks][j];
                sum_[mt] += a;
                ssq_[mt] += a * a;
            }
        }

    // ---- LN stats via cross-quad shuffle reduce (lanes l15, +16, +32, +48) ----
    // Row v=mt*16+l15's 64 channels live across the 4 quad-lanes: xor-16 + xor-32.
    float muv[2], rsv[2];
    #pragma unroll
    for (int mt = 0; mt < 2; mt++) {
        sum_[mt] += __shfl_xor(sum_[mt], 16);
        sum_[mt] += __shfl_xor(sum_[mt], 32);
        ssq_[mt] += __shfl_xor(ssq_[mt], 16);
        ssq_[mt] += __shfl_xor(ssq_[mt], 32);
        muv[mt] = sum_[mt] * 0.015625f;
        rsv[mt] = rsqrtf(ssq_[mt] * 0.015625f - muv[mt] * muv[mt] + EPSV);
    }

    // ---- normalize in-register -> yn A-frags ----
    bf16x8 yna[2][2];
    #pragma unroll
    for (int ks = 0; ks < 2; ks++) {
        f32x4 ga = *(const f32x4*)&ln_g[ks * 32 + quad * 8];
        f32x4 gb = *(const f32x4*)&ln_g[ks * 32 + quad * 8 + 4];
        f32x4 ba = *(const f32x4*)&ln_b[ks * 32 + quad * 8];
        f32x4 bb = *(const f32x4*)&ln_b[ks * 32 + quad * 8 + 4];
        #pragma unroll
        for (int mt = 0; mt < 2; mt++) {
            float yv[8];
            #pragma unroll
            for (int j = 0; j < 8; j++) {
                float g = (j < 4) ? ga[j] : gb[j - 4];
                float bt = (j < 4) ? ba[j] : bb[j - 4];
                yv[j] = (xf[mt][ks][j] - muv[mt]) * rsv[mt] * g + bt;
            }
            i32x4 p;
            #pragma unroll
            for (int q = 0; q < 4; q++) p[q] = pack2(yv[2 * q], yv[2 * q + 1]);
            yna[mt][ks] = __builtin_bit_cast(bf16x8, p);
        }
    }

    // ---- accumulators ----
    f32x4 acc[2][4];
    #pragma unroll
    for (int mt = 0; mt < 2; mt++)
        #pragma unroll
        for (int nt = 0; nt < 4; nt++)
            acc[mt][nt] = (f32x4){0.f, 0.f, 0.f, 0.f};

    const f32x4 z4 = {0.f, 0.f, 0.f, 0.f};
    const bf16x8 z8 = {0, 0, 0, 0, 0, 0, 0, 0};

    // per-lane swizzled-address constants (loop-invariant)
    const int sw4 = (l15 >> 2) & 3;
    const int blkA = ((r32 >> 3) ^ hi) << 4;
    unsigned char* gwA = ghb + hi * 256 + (r32 & 7) * 2 + blkA;         // dots write, (r>>2)&1==0
    unsigned char* gwB = ghb + hi * 256 + (r32 & 7) * 2 + (blkA ^ 32);  // dots write, (r>>2)&1==1
    unsigned char* w0p = fwb + ((((quad >> 1) ^ sw4)) << 4) + (quad & 1) * 8;       // FW cols quad*4
    unsigned char* w1p = fwb + (((((quad >> 1) ^ sw4)) ^ 2) << 4) + (quad & 1) * 8; // FW cols 16+quad*4
    unsigned char* brp = fwb + l15 * 64 + ((quad ^ sw4) << 4);                      // FW B-frag read

    // ---- head-pair loop (fully unrolled; global prefetches placed to hide latency) ----
    #pragma unroll
    for (int hp = 0; hp < 4; hp++) {
        // qk tiles: q-tile nt=hp (SCALE*log2e folded), k-tile nt=4+hp
        #pragma unroll
        for (int tsel = 0; tsel < 2; tsel++) {
            int nt = tsel ? (4 + hp) : hp;
            bf16x8 b0 = *(const bf16x8*)&wqk[(nt * 2 + 0) * 512 + lane * 8];
            bf16x8 b1 = *(const bf16x8*)&wqk[(nt * 2 + 1) * 512 + lane * 8];
            float bias = b_qk[(tsel ? 64 : 0) + hp * 16 + l15];
            unsigned short* buf = tsel ? kbuf : qbuf;
            #pragma unroll
            for (int mt = 0; mt < 2; mt++) {
                f32x4 d = __builtin_amdgcn_mfma_f32_16x16x32_bf16(yna[mt][0], b0, z4, 0, 0, 0);
                d = __builtin_amdgcn_mfma_f32_16x16x32_bf16(yna[mt][1], b1, d, 0, 0, 0);
                #pragma unroll
                for (int r = 0; r < 4; r++) {
                    int u = mt * 16 + quad * 4 + r;
                    if (u < 25) {
                        float val = d[r] + bias;
                        if (!tsel) val *= SCALE_L2E;
                        buf[u * 24 + l15] = bfh(val);
                    }
                }
            }
        }
        LGKM0();

        // dots: per head one 32x32x16 MFMA (K=8 real + 8 zero); swizzled Gh writes
        #pragma unroll
        for (int hh = 0; hh < 2; hh++) {
            bf16x8 aq = z8, bk = z8;
            if (hi == 0) {
                aq = *(const bf16x8*)&qbuf[r32 * 24 + hh * 8];
                bk = *(const bf16x8*)&kbuf[r32 * 24 + hh * 8];
            }
            f32x16 dd = {0.f,0.f,0.f,0.f,0.f,0.f,0.f,0.f,0.f,0.f,0.f,0.f,0.f,0.f,0.f,0.f};
            dd = __builtin_amdgcn_mfma_f32_32x32x16_bf16(aq, bk, dd, 0, 0, 0);
            #pragma unroll
            for (int r = 0; r < 16; r++) {
                int ub = (r & 3) + 8 * (r >> 2);
                if (ub + 4 * hi < 25) {
                    unsigned char* p = (((r >> 2) & 1) ? gwB : gwA) + hh * 2048 + ub * 64;
                    *(unsigned short*)p = bfh(dd[r]);
                }
            }
        }

        // prefetch this hp's topo row NOW (vmcnt load; latency hides under the
        // lgkm wait + softmax unpack VALU)
        float tpv[25];
        {
            const float* tp = topo + (hp * 2 + hi) * 625 + (r32 < 25 ? r32 : 0) * 25;
            #pragma unroll
            for (int v = 0; v < 25; v++) tpv[v] = tp[v];
        }
        LGKM0();

        // softmax * topo (50 active lanes: 2 heads x 25 rows), in-place, pad cols zeroed
        {
            int smh = hi, su = r32;
            if (su < 25) {
                unsigned char* rowb = ghb + smh * 2048 + su * 64;
                int sz = ((su >> 2) & 3) << 4;
                i32x4 ra = *(const i32x4*)(rowb + (sz ^ 0));
                i32x4 rb = *(const i32x4*)(rowb + (sz ^ 16));
                i32x4 rc = *(const i32x4*)(rowb + (sz ^ 32));
                float f[25];
                #pragma unroll
                for (int w = 0; w < 4; w++) {
                    f[2 * w]      = __builtin_bit_cast(float, (unsigned)ra[w] << 16);
                    f[2 * w + 1]  = __builtin_bit_cast(float, (unsigned)ra[w] & 0xFFFF0000u);
                    f[8 + 2 * w]  = __builtin_bit_cast(float, (unsigned)rb[w] << 16);
                    f[9 + 2 * w]  = __builtin_bit_cast(float, (unsigned)rb[w] & 0xFFFF0000u);
                    f[16 + 2 * w] = __builtin_bit_cast(float, (unsigned)rc[w] << 16);
                    f[17 + 2 * w] = __builtin_bit_cast(float, (unsigned)rc[w] & 0xFFFF0000u);
                }
                f[24] = bf2f(*(const unsigned short*)(rowb + (sz ^ 48)));
                // tree max
                float g12[12];
                #pragma unroll
                for (int i2 = 0; i2 < 12; i2++) g12[i2] = fmaxf(f[i2], f[i2 + 12]);
                #pragma unroll
                for (int i2 = 0; i2 < 6; i2++) g12[i2] = fmaxf(g12[i2], g12[i2 + 6]);
                float m = fmaxf(fmaxf(fmaxf(g12[0], g12[1]), fmaxf(g12[2], g12[3])),
                                fmaxf(fmaxf(g12[4], g12[5]), f[24]));
                // exp2 (log2e pre-folded into q) + 4-way sum
                float s0 = 0.f, s1 = 0.f, s2 = 0.f, s3 = 0.f;
                #pragma unroll
                for (int v = 0; v < 24; v += 4) {
                    f[v]     = __builtin_amdgcn_exp2f(f[v] - m);     s0 += f[v];
                    f[v + 1] = __builtin_amdgcn_exp2f(f[v + 1] - m); s1 += f[v + 1];
                    f[v + 2] = __builtin_amdgcn_exp2f(f[v + 2] - m); s2 += f[v + 2];
                    f[v + 3] = __builtin_amdgcn_exp2f(f[v + 3] - m); s3 += f[v + 3];
                }
                f[24] = __builtin_amdgcn_exp2f(f[24] - m);
                float inv = __builtin_amdgcn_rcpf(((s0 + s1) + (s2 + s3)) + f[24]);
                #pragma unroll
                for (int v = 0; v < 25; v++) f[v] = f[v] * inv * tpv[v];
                int d[12];
                #pragma unroll
                for (int p = 0; p < 12; p++) d[p] = pack2(f[2 * p], f[2 * p + 1]);
                *(i32x4*)(rowb + (sz ^ 0))  = (i32x4){d[0], d[1], d[2], d[3]};
                *(i32x4*)(rowb + (sz ^ 16)) = (i32x4){d[4], d[5], d[6], d[7]};
                *(i32x4*)(rowb + (sz ^ 32)) = (i32x4){d[8], d[9], d[10], d[11]};
                *(i32x4*)(rowb + (sz ^ 48)) = (i32x4){pack2(f[24], 0.f), 0, 0, 0};
            }
        }

        // early-issue W2^T frags for hh=0 (vmcnt; hides under the wait below)
        bf16x8 w2e[8];
        #pragma unroll
        for (int nt = 0; nt < 4; nt++) {
            int h = hp * 2;
            w2e[2 * nt]     = *(const bf16x8*)&w2f[((h * 4 + nt) * 2 + 0) * 512 + lane * 8];
            w2e[2 * nt + 1] = *(const bf16x8*)&w2f[((h * 4 + nt) * 2 + 1) * 512 + lane * 8];
        }
        LGKM0();

        // ---- FW hh=0: FW = feat @ W2ᵀ (w2e pre-issued) -> FWT swizzled ----
        #pragma unroll
        for (int nt = 0; nt < 4; nt++) {
            f32x4 dw0 = __builtin_amdgcn_mfma_f32_16x16x32_bf16(xa[0][0], w2e[2 * nt], z4, 0, 0, 0);
            dw0 = __builtin_amdgcn_mfma_f32_16x16x32_bf16(xa[0][1], w2e[2 * nt + 1], dw0, 0, 0, 0);
            f32x4 dw1 = __builtin_amdgcn_mfma_f32_16x16x32_bf16(xa[1][0], w2e[2 * nt], z4, 0, 0, 0);
            dw1 = __builtin_amdgcn_mfma_f32_16x16x32_bf16(xa[1][1], w2e[2 * nt + 1], dw1, 0, 0, 0);
            i32x2 q0 = {pack2(dw0[0], dw0[1]), pack2(dw0[2], dw0[3])};
            i32x2 q1 = {pack2(dw1[0], dw1[1]), pack2(dw1[2], dw1[3])};
            *(i32x2*)(w0p + nt * 1024 + l15 * 64) = q0;
            *(i32x2*)(w1p + nt * 1024 + l15 * 64) = q1;
        }
        // early-issue W2^T frags for hh=1 (hides under hh=0's wait + PV)
        bf16x8 w2o[8];
        #pragma unroll
        for (int nt = 0; nt < 4; nt++) {
            int h = hp * 2 + 1;
            w2o[2 * nt]     = *(const bf16x8*)&w2f[((h * 4 + nt) * 2 + 0) * 512 + lane * 8];
            w2o[2 * nt + 1] = *(const bf16x8*)&w2f[((h * 4 + nt) * 2 + 1) * 512 + lane * 8];
        }
        LGKM0();

        // ---- PV hh=0: acc += G_0 @ FW_0 ----
        {
            unsigned char* agp = ghb + l15 * 64 + ((quad ^ sw4) << 4);
            bf16x8 ag0 = *(const bf16x8*)agp;
            bf16x8 ag1 = *(const bf16x8*)(agp + 1024);
            #pragma unroll
            for (int nt = 0; nt < 4; nt++) {
                bf16x8 br = *(const bf16x8*)(brp + nt * 1024);
                acc[0][nt] = __builtin_amdgcn_mfma_f32_16x16x32_bf16(ag0, br, acc[0][nt], 0, 0, 0);
                acc[1][nt] = __builtin_amdgcn_mfma_f32_16x16x32_bf16(ag1, br, acc[1][nt], 0, 0, 0);
            }
        }

        // ---- FW hh=1 -> FWT (same-wave DS ordering keeps this after PV0's reads) ----
        #pragma unroll
        for (int nt = 0; nt < 4; nt++) {
            f32x4 dw0 = __builtin_amdgcn_mfma_f32_16x16x32_bf16(xa[0][0], w2o[2 * nt], z4, 0, 0, 0);
            dw0 = __builtin_amdgcn_mfma_f32_16x16x32_bf16(xa[0][1], w2o[2 * nt + 1], dw0, 0, 0, 0);
            f32x4 dw1 = __builtin_amdgcn_mfma_f32_16x16x32_bf16(xa[1][0], w2o[2 * nt], z4, 0, 0, 0);
            dw1 = __builtin_amdgcn_mfma_f32_16x16x32_bf16(xa[1][1], w2o[2 * nt + 1], dw1, 0, 0, 0);
            i32x2 q0 = {pack2(dw0[0], dw0[1]), pack2(dw0[2], dw0[3])};
            i32x2 q1 = {pack2(dw1[0], dw1[1]), pack2(dw1[2], dw1[3])};
            *(i32x2*)(w0p + nt * 1024 + l15 * 64) = q0;
            *(i32x2*)(w1p + nt * 1024 + l15 * 64) = q1;
        }
        LGKM0();

        // ---- PV hh=1: acc += G_1 @ FW_1 ----
        {
            unsigned char* agp = ghb + 2048 + l15 * 64 + ((quad ^ sw4) << 4);
            bf16x8 ag0 = *(const bf16x8*)agp;
            bf16x8 ag1 = *(const bf16x8*)(agp + 1024);
            #pragma unroll
            for (int nt = 0; nt < 4; nt++) {
                bf16x8 br = *(const bf16x8*)(brp + nt * 1024);
                acc[0][nt] = __builtin_amdgcn_mfma_f32_16x16x32_bf16(ag0, br, acc[0][nt], 0, 0, 0);
                acc[1][nt] = __builtin_amdgcn_mfma_f32_16x16x32_bf16(ag1, br, acc[1][nt], 0, 0, 0);
            }
        }
    }

    // ---- epilogue: BN + residual + ReLU, direct global store ----
    #pragma unroll
    for (int nt = 0; nt < 4; nt++) {
        int o = nt * 16 + l15;
        float gA = bnA[o], gB = bnB[o];
        #pragma unroll
        for (int mt = 0; mt < 2; mt++) {
            int ub = mt * 16 + quad * 4;
            #pragma unroll
            for (int r = 0; r < 4; r++) {
                int u = ub + r;
                if (u < 25) {
                    float val = acc[mt][nt][r] * gA + gB + xg[o * 6400 + u];
                    og[o * 6400 + u] = fmaxf(val, 0.f);
                }
            }
        }
    }
}

extern "C" void kernel_launch(void* const* d_in, const int* in_sizes, int n_in,
                              void* d_out, int out_size, void* d_ws, size_t ws_size,
                              hipStream_t stream) {
    const float* x      = (const float*)d_in[0];
    const float* ln_g   = (const float*)d_in[1];
    const float* ln_b   = (const float*)d_in[2];
    const float* w_qk   = (const float*)d_in[3];
    const float* b_qk   = (const float*)d_in[4];
    const float* topo   = (const float*)d_in[5];
    const float* conv_w = (const float*)d_in[6];
    const float* conv_b = (const float*)d_in[7];
    const float* bn_g   = (const float*)d_in[8];
    const float* bn_b   = (const float*)d_in[9];
    const float* bn_m   = (const float*)d_in[10];
    const float* bn_v   = (const float*)d_in[11];
    float* outp = (float*)d_out;
    unsigned short* wsp = (unsigned short*)d_ws;

    hipLaunchKernelGGL(prep_kernel, dim3(161), dim3(256), 0, stream,
                       w_qk, conv_w, conv_b, bn_g, bn_b, bn_m, bn_v, wsp);
    hipLaunchKernelGGL(sagc_kernel, dim3(2048), dim3(256), 0, stream,
                       x, ln_g, ln_b, b_qk, topo, (const unsigned short*)wsp, outp);
}